// Round 13
// baseline (23.521 us; speedup 1.0000x reference)
//
#include <hip/hip_runtime.h>
#include <hip/hip_bf16.h>
#include <stdint.h>

#define NI 256
#define NT 256
#define NL 25
#define NE 128
#define NHW 49
#define NTL (NT*NL)   // 6400

#define WAVES 8            // waves (=images) per match WG
#define CH_T 16            // texts per chunk
#define CH_TILES 25        // 16-row B tiles per chunk

typedef __attribute__((ext_vector_type(4))) int i32x4;

__device__ __forceinline__ int pack4(int q0, int q1, int q2, int q3) {
    return (q0 & 255) | ((q1 & 255) << 8) | ((q2 & 255) << 16) | ((q3 & 255) << 24);
}

// ---- Prep (identical to round 12) ----
__global__ __launch_bounds__(256) void prep_kernel(
    const float* __restrict__ emb, const int* __restrict__ text,
    const float* __restrict__ img,
    char* __restrict__ tf3, char* __restrict__ P2, char* __restrict__ P48,
    float* __restrict__ tfs, float* __restrict__ pscale)
{
    __shared__ float tile[NE * NHW];
    __shared__ float red[256];
    const int bid = blockIdx.x;
    const int tid = threadIdx.x;

    if (bid < 400) {
        // text tile: 16 rows x 128 elems; thread = (row r, sub)
        int r   = tid >> 4;
        int sub = tid & 15;
        int row = bid * 16 + r;
        int tok = text[row];
        const float4* e4 = reinterpret_cast<const float4*>(emb + (size_t)tok * NE + sub * 8);
        float4 f0 = e4[0], f1 = e4[1];
        float m = fmaxf(fmaxf(fmaxf(fabsf(f0.x), fabsf(f0.y)), fmaxf(fabsf(f0.z), fabsf(f0.w))),
                        fmaxf(fmaxf(fabsf(f1.x), fabsf(f1.y)), fmaxf(fabsf(f1.z), fabsf(f1.w))));
        m = fmaxf(m, __shfl_xor(m, 1));
        m = fmaxf(m, __shfl_xor(m, 2));
        m = fmaxf(m, __shfl_xor(m, 4));
        m = fmaxf(m, __shfl_xor(m, 8));
        float s = (m > 0.f) ? 127.f / m : 0.f;
        if (sub == 0) tfs[row] = m / 127.f;
        int q0 = __float2int_rn(f0.x * s), q1 = __float2int_rn(f0.y * s);
        int q2 = __float2int_rn(f0.z * s), q3 = __float2int_rn(f0.w * s);
        int q4 = __float2int_rn(f1.x * s), q5 = __float2int_rn(f1.y * s);
        int q6 = __float2int_rn(f1.z * s), q7 = __float2int_rn(f1.w * s);
        int2 o = make_int2(pack4(q0, q1, q2, q3), pack4(q4, q5, q6, q7));
        int kh  = sub >> 3;
        int lhi = (sub >> 1) & 3;
        size_t addr = ((size_t)(bid * 2 + kh) * 64 + lhi * 16 + r) * 16 + (sub & 1) * 8;
        *reinterpret_cast<int2*>(tf3 + addr) = o;
    } else {
        int i = bid - 400;
        const float4* src4 = reinterpret_cast<const float4*>(img + (size_t)i * NE * NHW);
        float4* tile4 = reinterpret_cast<float4*>(tile);
        for (int idx = tid; idx < NE * NHW / 4; idx += 256) tile4[idx] = src4[idx];
        __syncthreads();
        float lm = 0.f;
        for (int idx = tid; idx < NE * NHW; idx += 256) lm = fmaxf(lm, fabsf(tile[idx]));
        red[tid] = lm;
        __syncthreads();
        #pragma unroll
        for (int st = 128; st > 0; st >>= 1) {
            if (tid < st) red[tid] = fmaxf(red[tid], red[tid + st]);
            __syncthreads();
        }
        float pmax = red[0];
        float s = (pmax > 0.f) ? 127.f / pmax : 0.f;
        if (tid == 0) pscale[i] = pmax / 127.f;

        for (int idx = tid; idx < 384; idx += 256) {
            int f = idx >> 6, lane = idx & 63;
            int mt = f >> 1, kh = f & 1;
            int lr = lane & 15, lhi = lane >> 4;
            int p = mt * 16 + lr;              // 0..47, all real
            int d[4];
            #pragma unroll
            for (int w = 0; w < 4; w++) {
                int e = kh * 64 + lhi * 16 + w * 4;
                d[w] = pack4(__float2int_rn(tile[(e + 0) * NHW + p] * s),
                             __float2int_rn(tile[(e + 1) * NHW + p] * s),
                             __float2int_rn(tile[(e + 2) * NHW + p] * s),
                             __float2int_rn(tile[(e + 3) * NHW + p] * s));
            }
            i32x4 o = { d[0], d[1], d[2], d[3] };
            *reinterpret_cast<i32x4*>(P2 + ((size_t)(i * 6 + f) * 64 + lane) * 16) = o;
        }
        if (tid < 8) {
            int kh = tid & 1, lhi = (tid >> 1) & 3;
            int g = i >> 3, lr0 = i & 7;
            int d[4];
            #pragma unroll
            for (int w = 0; w < 4; w++) {
                int e = kh * 64 + lhi * 16 + w * 4;
                d[w] = pack4(__float2int_rn(tile[(e + 0) * NHW + 48] * s),
                             __float2int_rn(tile[(e + 1) * NHW + 48] * s),
                             __float2int_rn(tile[(e + 2) * NHW + 48] * s),
                             __float2int_rn(tile[(e + 3) * NHW + 48] * s));
            }
            i32x4 o = { d[0], d[1], d[2], d[3] };
            *reinterpret_cast<i32x4*>(P48 + ((size_t)(g * 2 + kh) * 64 + lhi * 16 + lr0) * 16) = o;
        }
    }
}

// ---- Match: i8 MFMA, 3-deep B-prefetch + one-tile-deferred reduce ----
// 512 WGs = 32 image-groups (8 images) x 16 text-chunks; wave = 1 image.
// Tile j's B-load issues 2 compute-phases ahead (T0/T1/T2 rotation, static
// indexing); tile j's reduce issues after tile j+1's MFMA cluster (aA/aB
// swap) so VALU reduce overlaps matrix-pipe work instead of stalling on it.
__global__ __launch_bounds__(512, 4) void match_kernel(
    const char* __restrict__ tf3,
    const char* __restrict__ P2,
    const char* __restrict__ P48,
    const float* __restrict__ tfs,
    const float* __restrict__ pscale,
    const int* __restrict__ text_length,
    const float* __restrict__ logit_scale,
    float* __restrict__ out)
{
    __shared__ int vals[WAVES][CH_TILES][64];   // per-lane 12-patch int max
    __shared__ int vals48[CH_TILES][128];       // [j][imgrow*16+textcol]

    const int ig   = blockIdx.x & 31;    // image group (8 images)
    const int tq   = blockIdx.x >> 5;    // text chunk (16 texts = 25 tiles)
    const int tid  = threadIdx.x;
    const int wave = tid >> 6;
    const int lane = tid & 63;
    const int lr   = lane & 15;
    const int lhi  = lane >> 4;

    const int img = ig * WAVES + wave;
    const i32x4* p2 = reinterpret_cast<const i32x4*>(P2) + (size_t)img * 6 * 64 + lane;
    i32x4 pf[6];
    #pragma unroll
    for (int f = 0; f < 6; f++) pf[f] = p2[f * 64];
    #pragma unroll
    for (int f = 0; f < 6; f++) asm volatile("" : "+v"(pf[f]));

    const i32x4* p48 = reinterpret_cast<const i32x4*>(P48) + (size_t)ig * 2 * 64 + lane;

    i32x4 zc = { 0, 0, 0, 0 };
    asm volatile("" : "+v"(zc));

    const char* tb = tf3 + (size_t)tq * CH_TILES * 2048 + lane * 16;

    auto loadT = [&](i32x4* T, int jl) {
        jl = (jl > 24) ? 24 : jl;   // clamped dead loads at the tail
        T[0] = *reinterpret_cast<const i32x4*>(tb + jl * 2048);
        T[1] = *reinterpret_cast<const i32x4*>(tb + jl * 2048 + 1024);
    };

    auto imax = [](int a, int b) { return a > b ? a : b; };

    // MFMA cluster for tile jl (+ duty patch-48 tile); no reduce here.
    auto mfma_tile = [&](i32x4* acc, const i32x4* T, int jl) {
        __builtin_amdgcn_s_setprio(1);
        acc[0] = __builtin_amdgcn_mfma_i32_16x16x64_i8(pf[0], T[0], zc, 0, 0, 0);
        acc[1] = __builtin_amdgcn_mfma_i32_16x16x64_i8(pf[2], T[0], zc, 0, 0, 0);
        acc[2] = __builtin_amdgcn_mfma_i32_16x16x64_i8(pf[4], T[0], zc, 0, 0, 0);
        acc[0] = __builtin_amdgcn_mfma_i32_16x16x64_i8(pf[1], T[1], acc[0], 0, 0, 0);
        acc[1] = __builtin_amdgcn_mfma_i32_16x16x64_i8(pf[3], T[1], acc[1], 0, 0, 0);
        acc[2] = __builtin_amdgcn_mfma_i32_16x16x64_i8(pf[5], T[1], acc[2], 0, 0, 0);
        if ((jl & 7) == wave) {
            i32x4 d = __builtin_amdgcn_mfma_i32_16x16x64_i8(p48[0],  T[0], zc, 0, 0, 0);
            d = __builtin_amdgcn_mfma_i32_16x16x64_i8(p48[64], T[1], d, 0, 0, 0);
            __builtin_amdgcn_s_setprio(0);
            if (lhi < 2) {
                #pragma unroll
                for (int r = 0; r < 4; r++)
                    vals48[jl][(lhi * 4 + r) * 16 + lr] = d[r];
            }
        } else {
            __builtin_amdgcn_s_setprio(0);
        }
    };

    // Reduce tile jl's acc (issued one tile later -> MFMA results complete).
    auto reduce_tile = [&](const i32x4* a, int jl) {
        int r1 = imax(imax(a[0][0], a[0][1]), a[0][2]);
        int r2 = imax(imax(a[0][3], a[1][0]), a[1][1]);
        int r3 = imax(imax(a[1][2], a[1][3]), a[2][0]);
        int r4 = imax(imax(a[2][1], a[2][2]), a[2][3]);
        vals[wave][jl][lane] = imax(imax(r1, r2), imax(r3, r4));
    };

    i32x4 T0[2], T1[2], T2[2];
    i32x4 aA[3], aB[3];
    loadT(T0, 0);
    loadT(T1, 1);
    loadT(T2, 2);
    mfma_tile(aA, T0, 0);
    // Steady state (6 tiles/iter): tile j in buffer T[j%3]; load j+2 issued
    // before tile j's MFMAs; reduce of j-1 after tile j's MFMAs.
    #pragma unroll 1
    for (int jj = 0; jj < 4; jj++) {
        const int j0 = jj * 6;
        loadT(T0, j0 + 3); mfma_tile(aB, T1, j0 + 1); reduce_tile(aA, j0);
        loadT(T1, j0 + 4); mfma_tile(aA, T2, j0 + 2); reduce_tile(aB, j0 + 1);
        loadT(T2, j0 + 5); mfma_tile(aB, T0, j0 + 3); reduce_tile(aA, j0 + 2);
        loadT(T0, j0 + 6); mfma_tile(aA, T1, j0 + 4); reduce_tile(aB, j0 + 3);
        loadT(T1, j0 + 7); mfma_tile(aB, T2, j0 + 5); reduce_tile(aA, j0 + 4);
        loadT(T2, j0 + 8); mfma_tile(aA, T0, j0 + 6); reduce_tile(aB, j0 + 5);
    }
    reduce_tile(aA, 24);
    __syncthreads();

    // Epilogue: int max over 4 lane-groups + duty row, descale, sum, scale.
    if (tid < WAVES * CH_T) {
        int g  = tid >> 4;
        int tl = tid & 15;
        float simg = pscale[ig * WAVES + g];
        const float* tf_s = tfs + tq * 400;
        float s = 0.f;
        #pragma unroll
        for (int l = 0; l < 25; l++) {
            int row = tl * 25 + l;          // text row within chunk, 0..399
            int j = row >> 4;
            int r = row & 15;
            int m0 = imax(vals[g][j][r],      vals[g][j][r + 16]);
            int m1 = imax(vals[g][j][r + 32], vals[g][j][r + 48]);
            int mm = imax(imax(m0, m1), vals48[j][g * 16 + r]);
            s += (float)mm * tf_s[row];
        }
        int t = tq * CH_T + tl;
        int i = ig * WAVES + g;
        float val = s * simg / (float)text_length[t] * expf(logit_scale[0]);
        out[(size_t)i * NT + t] = val;                      // logits_per_image [I,T]
        out[(size_t)NI * NT + (size_t)t * NI + i] = val;    // logits_per_text  [T,I]
    }
}

extern "C" void kernel_launch(void* const* d_in, const int* in_sizes, int n_in,
                              void* d_out, int out_size, void* d_ws, size_t ws_size,
                              hipStream_t stream)
{
    const float* img  = (const float*)d_in[0];   // [256,128,7,7]
    const float* emb  = (const float*)d_in[1];   // [10000,128]
    const float* ls   = (const float*)d_in[2];   // scalar
    const int*   text = (const int*)d_in[3];     // [256,25]
    const int*   tlen = (const int*)d_in[4];     // [256]
    float* out = (float*)d_out;

    char* ws = (char*)d_ws;
    char*  tf3    = ws;                          //   819,200 B (i8 B-fragments)
    char*  P2     = ws + 819200;                 // 1,572,864 B (i8 A-fragments)
    char*  P48    = ws + 2392064;                //    65,536 B (packed patch-48)
    float* tfs    = (float*)(ws + 2457600);      //    25,600 B (per-word scales)
    float* pscale = (float*)(ws + 2483200);      //     1,024 B (per-image scales)

    prep_kernel<<<656, 256, 0, stream>>>(emb, text, img, tf3, P2, P48, tfs, pscale);
    match_kernel<<<512, 512, 0, stream>>>(tf3, P2, P48, tfs, pscale, tlen, ls, out);
}